// Round 1
// 1151.425 us; speedup vs baseline: 1.0171x; 1.0171x over previous
//
#include <hip/hip_runtime.h>
#include <cstdint>
#include <cstddef>

#define N_NODES 20000
#define F_IN    8710
#define HID     128
#define NCLS    70
#define NCP     96             // padded bf16 row for h2: 192 B = 3 aligned cache lines
#define NEDGE   640000
#define KTILES  137            // ceil(8710/64)
#define KPAD    (KTILES * 64)  // 8768
#define BK      64
#define SPLITK  8

typedef __attribute__((ext_vector_type(4))) float f32x4;
typedef __attribute__((ext_vector_type(8))) short bf16x8;

// ---- fp32 -> bf16 RNE, bit math ----
__device__ inline unsigned short f2bf(float f) {
    unsigned int u = __float_as_uint(f);
    u += 0x7fffu + ((u >> 16) & 1u);
    return (unsigned short)(u >> 16);
}

// pack 2 fp32 -> 2 bf16 (lo=a, hi=b)
#if __has_builtin(__builtin_amdgcn_cvt_pk_bf16_f32)
typedef __attribute__((ext_vector_type(2))) __bf16 bf16x2t;
__device__ inline unsigned int pk2(float a, float b) {
    union { bf16x2t v; unsigned int u; } c;
    c.v = __builtin_amdgcn_cvt_pk_bf16_f32(a, b);
    return c.u;
}
#else
__device__ inline unsigned int pk2(float a, float b) {
    unsigned int ua = __float_as_uint(a), ub = __float_as_uint(b);
    ua += 0x7fffu + ((ua >> 16) & 1u);
    ub += 0x7fffu + ((ub >> 16) & 1u);
    return (ua >> 16) | (ub & 0xffff0000u);
}
#endif

// unpack 2 bf16 (in one u32) -> fp32, exact
__device__ inline float bflo(unsigned int u) { return __uint_as_float(u << 16); }
__device__ inline float bfhi(unsigned int u) { return __uint_as_float(u & 0xffff0000u); }

// K0: W1 [F_IN][HID] -> W1T bf16 [HID][KPAD], coalesced via LDS transpose.
__global__ __launch_bounds__(256) void prep_w1t(const float* __restrict__ W1,
                                                unsigned short* __restrict__ w1t) {
    __shared__ float tl[64][65];
    int t = threadIdx.x;
    int k0 = blockIdx.x * 64, n0 = blockIdx.y * 64;
#pragma unroll
    for (int j = 0; j < 16; j++) {
        int l = j * 256 + t;
        int k = l >> 6, n = l & 63;
        float v = 0.0f;
        if (k0 + k < F_IN) v = W1[(size_t)(k0 + k) * HID + n0 + n];
        tl[k][n] = v;
    }
    __syncthreads();
#pragma unroll
    for (int j = 0; j < 16; j++) {
        int l = j * 256 + t;
        int n = l >> 6, k = l & 63;
        w1t[(size_t)(n0 + n) * KPAD + k0 + k] = f2bf(tl[k][n]);
    }
}

// K1: zero edge-count histogram
__global__ void zero_cnt(int* __restrict__ cnt) {
    int i = blockIdx.x * 256 + threadIdx.x;
    if (i < N_NODES) cnt[i] = 0;
}

// K2: histogram of dst
__global__ void count_deg(const int* __restrict__ edges, int* __restrict__ cnt) {
    int e = blockIdx.x * 256 + threadIdx.x;
    if (e < NEDGE) atomicAdd(&cnt[edges[NEDGE + e]], 1);
}

// K3: single-block exclusive scan -> rowptr, cursor; dinv = rsqrt(1+cnt)
#define SCAN_CH 20
__global__ __launch_bounds__(1024) void scan_k(const int* __restrict__ cnt,
                                               int* __restrict__ rowptr,
                                               int* __restrict__ cursor,
                                               float* __restrict__ dinv) {
    __shared__ int sums[1024];
    int t = threadIdx.x;
    int base = t * SCAN_CH;
    int s = 0;
    for (int j = 0; j < SCAN_CH; j++) {
        int i = base + j;
        if (i < N_NODES) s += cnt[i];
    }
    sums[t] = s;
    __syncthreads();
    for (int off = 1; off < 1024; off <<= 1) {
        int v = (t >= off) ? sums[t - off] : 0;
        __syncthreads();
        sums[t] += v;
        __syncthreads();
    }
    int run = sums[t] - s;
    for (int j = 0; j < SCAN_CH; j++) {
        int i = base + j;
        if (i < N_NODES) {
            rowptr[i] = run;
            cursor[i] = run;
            int c = cnt[i];
            dinv[i] = rsqrtf(1.0f + (float)c);
            run += c;
        }
    }
    if (t == 1023) rowptr[N_NODES] = sums[1023];
}

// K4: scatter edges into CSR column array
__global__ void scatter_edges(const int* __restrict__ edges,
                              int* __restrict__ cursor,
                              int* __restrict__ colidx) {
    int e = blockIdx.x * 256 + threadIdx.x;
    if (e < NEDGE) {
        int s = edges[e];
        int d = edges[NEDGE + e];
        int pos = atomicAdd(&cursor[d], 1);
        colidx[pos] = s;
    }
}

// K5: GEMM1 hpart[z] = x @ W1, bf16 MFMA.  (unchanged this round)
__global__ __launch_bounds__(256, 3) void gemm1(const float* __restrict__ X,
                                                const unsigned short* __restrict__ W1T,
                                                float* __restrict__ outp) {
    __shared__ unsigned short sB[2 * 8192];  // 2 x (128 rows x 64 bf16) = 32 KB
    int tid = threadIdx.x;
    int lane = tid & 63;
    int wv = __builtin_amdgcn_readfirstlane(tid >> 6);
    int m0 = blockIdx.x * 128;
    int z = blockIdx.y;
    int t0 = (z * KTILES) / SPLITK, t1 = ((z + 1) * KTILES) / SPLITK;

    int goffs[4];
#pragma unroll
    for (int i = 0; i < 4; i++) {
        int p = i * 256 + wv * 64 + lane;
        int r = p >> 3;
        int jl = (p & 7) ^ (r & 7);
        goffs[i] = r * KPAD + jl * 8;
    }

    const float* aptr[2];
#pragma unroll
    for (int mt = 0; mt < 2; mt++) {
        int row = m0 + wv * 32 + mt * 16 + (lane & 15);
        row = row < N_NODES ? row : N_NODES - 1;
        aptr[mt] = X + (size_t)row * F_IN + ((lane >> 4) * 8);
    }

    f32x4 acc[2][8];
#pragma unroll
    for (int mt = 0; mt < 2; mt++)
#pragma unroll
        for (int nt = 0; nt < 8; nt++) acc[mt][nt] = (f32x4)0.0f;

    auto stageB = [&](int kt, int buf) {
        int k0s = kt * BK;
#pragma unroll
        for (int i = 0; i < 4; i++) {
            const unsigned short* g = W1T + k0s + goffs[i];
            unsigned short* l = &sB[buf * 8192 + (i * 256 + wv * 64) * 8];
            __builtin_amdgcn_global_load_lds(
                (const __attribute__((address_space(1))) unsigned int*)g,
                (__attribute__((address_space(3))) unsigned int*)l, 16, 0, 0);
        }
    };

    stageB(t0, 0);
    __syncthreads();
    int cur = 0;

    for (int kt = t0; kt < t1; kt++) {
        int k0 = kt * BK;
        float2 q[2][2][4];
#pragma unroll
        for (int mt = 0; mt < 2; mt++)
#pragma unroll
            for (int kh = 0; kh < 2; kh++)
#pragma unroll
                for (int h = 0; h < 4; h++)
                    q[mt][kh][h] = *(const float2*)(aptr[mt] + k0 + kh * 32 + h * 2);
        if (kt + 1 < t1) stageB(kt + 1, cur ^ 1);
        bf16x8 af[2][2];
#pragma unroll
        for (int mt = 0; mt < 2; mt++)
#pragma unroll
            for (int kh = 0; kh < 2; kh++) {
                union { bf16x8 v; unsigned int u[4]; } c;
#pragma unroll
                for (int h = 0; h < 4; h++) c.u[h] = pk2(q[mt][kh][h].x, q[mt][kh][h].y);
                af[mt][kh] = c.v;
            }
        const unsigned short* bb = &sB[cur * 8192];
#pragma unroll
        for (int kh = 0; kh < 2; kh++) {
            int jx = (kh * 4 + (lane >> 4)) ^ (lane & 7);
#pragma unroll
            for (int half = 0; half < 2; half++) {
                bf16x8 bf[4];
#pragma unroll
                for (int q4 = 0; q4 < 4; q4++) {
                    int r = (half * 4 + q4) * 16 + (lane & 15);
                    bf[q4] = *(const bf16x8*)&bb[(r * 8 + jx) * 8];
                }
#pragma unroll
                for (int mt = 0; mt < 2; mt++)
#pragma unroll
                    for (int q4 = 0; q4 < 4; q4++)
                        acc[mt][half * 4 + q4] = __builtin_amdgcn_mfma_f32_16x16x32_bf16(
                            af[mt][kh], bf[q4], acc[mt][half * 4 + q4], 0, 0, 0);
            }
        }
        __syncthreads();
        cur ^= 1;
    }

    float* out = outp + (size_t)z * N_NODES * HID;
    int ccol = lane & 15, crow4 = (lane >> 4) * 4;
#pragma unroll
    for (int mt = 0; mt < 2; mt++) {
#pragma unroll
        for (int j = 0; j < 4; j++) {
            int m = m0 + wv * 32 + mt * 16 + crow4 + j;
            if (m < N_NODES) {
#pragma unroll
                for (int nt = 0; nt < 8; nt++)
                    out[(size_t)m * HID + nt * 16 + ccol] = acc[mt][nt][j];
            }
        }
    }
}

// K6: reduce split-K partials (8-way) -> bf16 hlin1b (RNE), halves gather table to 5.12 MB
__global__ void reduce_k(const float* __restrict__ p, unsigned short* __restrict__ ob) {
    size_t idx = ((size_t)blockIdx.x * 256 + threadIdx.x) * 4;
    if (idx < (size_t)N_NODES * HID) {
        float4 a = *(const float4*)(p + idx);
#pragma unroll
        for (int z = 1; z < SPLITK; z++) {
            float4 b = *(const float4*)(p + (size_t)z * N_NODES * HID + idx);
            a.x += b.x; a.y += b.y; a.z += b.z; a.w += b.w;
        }
        uint2 o;
        o.x = pk2(a.x, a.y);
        o.y = pk2(a.z, a.w);
        *(uint2*)(&ob[idx]) = o;  // idx % 4 == 0 -> 8B aligned
    }
}

// K7: layer-1 aggregation + bias + relu. One wave/node, lane covers 2 features (1 u32 of bf16x2).
// Gather bytes per edge: 256 B (was 512 fp32). Accumulation stays fp32.
__global__ __launch_bounds__(256) void agg1(const unsigned short* __restrict__ hlinb,
                                            const int* __restrict__ rowptr,
                                            const int* __restrict__ colidx,
                                            const float* __restrict__ dinv,
                                            const float* __restrict__ b1,
                                            float* __restrict__ hout) {
    int node = blockIdx.x * 4 + (threadIdx.x >> 6);
    int lane = threadIdx.x & 63;
    if (node >= N_NODES) return;
    float di = dinv[node];
    unsigned int us = ((const unsigned int*)(hlinb + (size_t)node * HID))[lane];
    float2 acc;
    acc.x = di * bflo(us);
    acc.y = di * bfhi(us);
    int e0 = rowptr[node], e1 = rowptr[node + 1];
    int e = e0;
    for (; e + 4 <= e1; e += 4) {
        int s0 = colidx[e + 0], s1 = colidx[e + 1], s2 = colidx[e + 2], s3 = colidx[e + 3];
        float w0 = dinv[s0], w1 = dinv[s1], w2 = dinv[s2], w3 = dinv[s3];
        unsigned int u0 = ((const unsigned int*)(hlinb + (size_t)s0 * HID))[lane];
        unsigned int u1 = ((const unsigned int*)(hlinb + (size_t)s1 * HID))[lane];
        unsigned int u2 = ((const unsigned int*)(hlinb + (size_t)s2 * HID))[lane];
        unsigned int u3 = ((const unsigned int*)(hlinb + (size_t)s3 * HID))[lane];
        acc.x += w0 * bflo(u0); acc.y += w0 * bfhi(u0);
        acc.x += w1 * bflo(u1); acc.y += w1 * bfhi(u1);
        acc.x += w2 * bflo(u2); acc.y += w2 * bfhi(u2);
        acc.x += w3 * bflo(u3); acc.y += w3 * bfhi(u3);
    }
    for (; e < e1; e++) {
        int s = colidx[e];
        float w = dinv[s];
        unsigned int u = ((const unsigned int*)(hlinb + (size_t)s * HID))[lane];
        acc.x += w * bflo(u); acc.y += w * bfhi(u);
    }
    float2 b = ((const float2*)b1)[lane];
    float ox = di * acc.x + b.x;
    float oy = di * acc.y + b.y;
    ox = ox > 0.0f ? ox : 0.0f;
    oy = oy > 0.0f ? oy : 0.0f;
    ((float2*)(hout + (size_t)node * HID))[lane] = make_float2(ox, oy);
}

// K8: GEMM2 h2 = h1 @ W2 (tiny: LDS-staged fp32 VALU) -> bf16, rows padded to NCP=96
// (192 B rows = 3 aligned cache lines; table 3.84 MB -> per-XCD-L2 resident)
#define NPB 8
__global__ __launch_bounds__(256) void gemm2(const float* __restrict__ h1,
                                             const float* __restrict__ W2,
                                             unsigned short* __restrict__ h2b) {
    __shared__ float sW[HID * NCLS];
    __shared__ float sH[NPB * HID];
    int t = threadIdx.x;
    int n0 = blockIdx.x * NPB;
    for (int i = t; i < HID * NCLS; i += 256) sW[i] = W2[i];
    for (int i = t; i < NPB * HID; i += 256) sH[i] = h1[(size_t)n0 * HID + i];
    __syncthreads();
    for (int o = t; o < NPB * NCLS; o += 256) {
        int ln = o / NCLS, c = o % NCLS;
        const float* hr = &sH[ln * HID];
        float a = 0.0f;
#pragma unroll 8
        for (int k = 0; k < HID; k++) a += hr[k] * sW[k * NCLS + c];
        h2b[(size_t)(n0 + ln) * NCP + c] = f2bf(a);
    }
}

// K9: layer-2 aggregation + bias + softmax. One wave/node; lanes 0..34 hold 2 classes (1 u32).
// Gather bytes per edge: 140 B in 3 aligned lines (was ~280 B over ~5.4 unaligned lines).
__global__ __launch_bounds__(256) void agg2_softmax(const unsigned short* __restrict__ h2b,
                                                    const int* __restrict__ rowptr,
                                                    const int* __restrict__ colidx,
                                                    const float* __restrict__ dinv,
                                                    const float* __restrict__ b2,
                                                    float* __restrict__ outp) {
    int node = blockIdx.x * 4 + (threadIdx.x >> 6);
    int lane = threadIdx.x & 63;
    if (node >= N_NODES) return;
    float di = dinv[node];
    bool act = lane < 35;
    int lidx = act ? lane : 0;
    float2 acc = make_float2(0.0f, 0.0f);
    {
        unsigned int u = *(const unsigned int*)(h2b + (size_t)node * NCP + 2 * lidx);
        acc.x = di * bflo(u);
        acc.y = di * bfhi(u);
    }
    int e0 = rowptr[node], e1 = rowptr[node + 1];
    int e = e0;
    for (; e + 4 <= e1; e += 4) {
        int s0 = colidx[e + 0], s1 = colidx[e + 1], s2 = colidx[e + 2], s3 = colidx[e + 3];
        float w0 = dinv[s0], w1 = dinv[s1], w2 = dinv[s2], w3 = dinv[s3];
        unsigned int u0 = *(const unsigned int*)(h2b + (size_t)s0 * NCP + 2 * lidx);
        unsigned int u1 = *(const unsigned int*)(h2b + (size_t)s1 * NCP + 2 * lidx);
        unsigned int u2 = *(const unsigned int*)(h2b + (size_t)s2 * NCP + 2 * lidx);
        unsigned int u3 = *(const unsigned int*)(h2b + (size_t)s3 * NCP + 2 * lidx);
        acc.x += w0 * bflo(u0); acc.y += w0 * bfhi(u0);
        acc.x += w1 * bflo(u1); acc.y += w1 * bfhi(u1);
        acc.x += w2 * bflo(u2); acc.y += w2 * bfhi(u2);
        acc.x += w3 * bflo(u3); acc.y += w3 * bfhi(u3);
    }
    for (; e < e1; e++) {
        int s = colidx[e];
        float w = dinv[s];
        unsigned int u = *(const unsigned int*)(h2b + (size_t)s * NCP + 2 * lidx);
        acc.x += w * bflo(u); acc.y += w * bfhi(u);
    }
    float lx = -1e30f, ly = -1e30f;
    if (act) {
        float2 b = *(const float2*)(b2 + 2 * lane);
        lx = di * acc.x + b.x;
        ly = di * acc.y + b.y;
    }
    float mx = fmaxf(lx, ly);
#pragma unroll
    for (int off = 32; off > 0; off >>= 1) mx = fmaxf(mx, __shfl_xor(mx, off, 64));
    float ex = 0.0f, ey = 0.0f;
    if (act) {
        ex = __expf(lx - mx);
        ey = __expf(ly - mx);
    }
    float sm = ex + ey;
#pragma unroll
    for (int off = 32; off > 0; off >>= 1) sm += __shfl_xor(sm, off, 64);
    if (act) {
        float inv = 1.0f / sm;
        *(float2*)(outp + (size_t)node * NCLS + 2 * lane) = make_float2(ex * inv, ey * inv);
    }
}

extern "C" void kernel_launch(void* const* d_in, const int* in_sizes, int n_in,
                              void* d_out, int out_size, void* d_ws, size_t ws_size,
                              hipStream_t stream) {
    const float* x     = (const float*)d_in[0];
    const int*   edges = (const int*)d_in[1];
    const float* W1    = (const float*)d_in[2];
    const float* b1    = (const float*)d_in[3];
    const float* W2    = (const float*)d_in[4];
    const float* b2    = (const float*)d_in[5];
    float* outp = (float*)d_out;

    char* ws = (char*)d_ws;
    size_t off = 0;
    auto alloc = [&](size_t bytes) {
        void* p = ws + off;
        off += (bytes + 255) & ~(size_t)255;
        return p;
    };
    unsigned short* w1t  = (unsigned short*)alloc((size_t)HID * KPAD * 2);
    int*   cnt    = (int*)alloc((size_t)N_NODES * 4);
    int*   rowptr = (int*)alloc((size_t)(N_NODES + 1) * 4);
    int*   cursor = (int*)alloc((size_t)N_NODES * 4);
    float* dinv   = (float*)alloc((size_t)N_NODES * 4);
    int*   colidx = (int*)alloc((size_t)NEDGE * 4);
    float* hpart  = (float*)alloc((size_t)SPLITK * N_NODES * HID * 4);
    unsigned short* hlinb = (unsigned short*)alloc((size_t)N_NODES * HID * 2);
    float* h1     = (float*)alloc((size_t)N_NODES * HID * 4);
    unsigned short* h2b = (unsigned short*)alloc((size_t)N_NODES * NCP * 2);

    hipLaunchKernelGGL(prep_w1t, dim3(KTILES, 2), dim3(256), 0, stream, W1, w1t);
    hipLaunchKernelGGL(zero_cnt, dim3((N_NODES + 255) / 256), dim3(256), 0, stream, cnt);
    hipLaunchKernelGGL(count_deg, dim3((NEDGE + 255) / 256), dim3(256), 0, stream, edges, cnt);
    hipLaunchKernelGGL(scan_k, dim3(1), dim3(1024), 0, stream, cnt, rowptr, cursor, dinv);
    hipLaunchKernelGGL(scatter_edges, dim3((NEDGE + 255) / 256), dim3(256), 0, stream, edges, cursor, colidx);
    hipLaunchKernelGGL(gemm1, dim3((N_NODES + 127) / 128, SPLITK), dim3(256), 0, stream, x, w1t, hpart);
    hipLaunchKernelGGL(reduce_k, dim3((N_NODES * HID / 4 + 255) / 256), dim3(256), 0, stream, hpart, hlinb);
    hipLaunchKernelGGL(agg1, dim3((N_NODES + 3) / 4), dim3(256), 0, stream, hlinb, rowptr, colidx, dinv, b1, h1);
    hipLaunchKernelGGL(gemm2, dim3(N_NODES / NPB), dim3(256), 0, stream, h1, W2, h2b);
    hipLaunchKernelGGL(agg2_softmax, dim3((N_NODES + 3) / 4), dim3(256), 0, stream, h2b, rowptr, colidx, dinv, b2, outp);
}